// Round 17
// baseline (619.913 us; speedup 1.0000x reference)
//
#include <hip/hip_runtime.h>

typedef _Float16 half8_t __attribute__((ext_vector_type(8)));
typedef _Float16 half4_t __attribute__((ext_vector_type(4)));
typedef _Float16 half2_t __attribute__((ext_vector_type(2)));
typedef float f32x4 __attribute__((ext_vector_type(4)));

#define MFMA16(a, b, c) __builtin_amdgcn_mfma_f32_16x16x32_f16((a), (b), (c), 0, 0, 0)

typedef const unsigned int __attribute__((address_space(1)))* gas_ptr;
typedef unsigned int __attribute__((address_space(3)))* las_ptr;

__device__ __forceinline__ void gload16(const void* g, void* l) {
    __builtin_amdgcn_global_load_lds((gas_ptr)g, (las_ptr)l, 16, 0, 0);
}

// m204 bijective XCD swizzle: contiguous wgid chunk per XCD
__device__ __forceinline__ int xcd_swizzle(int bid, int nwg) {
    int xcd = bid & 7, i = bid >> 3;
    int q = nwg >> 3, r = nwg & 7;
    return (xcd < r ? xcd * (q + 1) : r * (q + 1) + (xcd - r) * q) + i;
}

// ---------------- fused prep: cvt x->f16 (grid-stride) + transpose w_qkv/w_proj ----
// blocks [0, 4096): cvt; [4096, 4096+6912): w_qkv^T; [4096+6912, 4096+6912+2304): w_proj^T
__global__ void prep_kernel(const float* __restrict__ x, _Float16* __restrict__ xh,
                            const float* __restrict__ w_qkv, _Float16* __restrict__ wqkvT,
                            const float* __restrict__ w_proj, _Float16* __restrict__ wprojT) {
    int blk = blockIdx.x;
    if (blk < 4096) {
        int stride = 4096 * 256;
        for (int i = blk * 256 + threadIdx.x; i < 9633792; i += stride) {
            f32x4 v = *(const f32x4*)(x + (size_t)4 * i);
            half4_t h;
            h[0] = (_Float16)v[0]; h[1] = (_Float16)v[1];
            h[2] = (_Float16)v[2]; h[3] = (_Float16)v[3];
            *(half4_t*)(xh + (size_t)4 * i) = h;
        }
    } else if (blk < 4096 + 6912) {
        int idx = (blk - 4096) * 256 + threadIdx.x;   // < 2304*768
        int j = idx / 768, k = idx - j * 768;
        wqkvT[idx] = (_Float16)w_qkv[(size_t)k * 2304 + j];
    } else {
        int idx = (blk - 4096 - 6912) * 256 + threadIdx.x;  // < 768*768
        int j = idx / 768, k = idx - j * 768;
        wprojT[idx] = (_Float16)w_proj[(size_t)k * 768 + j];
    }
}

// ---------------- GEMM core: m97-class 128x128 tile, 4 waves, BK=64, single-buffer ----
// (R12/R13/R14-verified best: 0 conflicts, 4 blocks/CU, MfmaUtil 28.5%)

#define STG128(kof)                                                               \
    {                                                                             \
        _Pragma("unroll")                                                         \
        for (int i = 0; i < 4; ++i) {                                             \
            gload16(ArowS + (kof) + i * 24576, As + wave * 512 + i * 2048);       \
            gload16(BrowS + (kof) + i * 24576, Bs + wave * 512 + i * 2048);       \
        }                                                                         \
    }

__device__ __forceinline__ void run_gemm128(const _Float16* __restrict__ A,
                                            const _Float16* __restrict__ Bt,
                                            int mbase, int nbase,
                                            _Float16* As, _Float16* Bs,   // 8192 f16 each
                                            f32x4 (&acc)[4][4]) {
    const int tid = threadIdx.x;
    const int lane = tid & 63;
    const int wave = tid >> 6;
    const int wm = (wave >> 1) * 64;
    const int wn = (wave & 1) * 64;
    const int l15 = lane & 15;
    const int l4 = lane >> 4;
    const int rs = l15 & 7;                                   // read swizzle key
    const int srow = lane >> 3;                               // staging row-in-8 (0..7)
    const int ssl = ((lane & 7) ^ srow) << 3;                 // staging source slot offset

    #pragma unroll
    for (int mi = 0; mi < 4; ++mi)
        #pragma unroll
        for (int ni = 0; ni < 4; ++ni)
            acc[mi][ni] = (f32x4){0.f, 0.f, 0.f, 0.f};

    const _Float16* ArowS = A + (size_t)(mbase + wave * 8 + srow) * 768 + ssl;
    const _Float16* BrowS = Bt + (size_t)(nbase + wave * 8 + srow) * 768 + ssl;

    for (int kt = 0; kt < 12; ++kt) {
        STG128(kt * 64)
        __syncthreads();
        #pragma unroll
        for (int h = 0; h < 2; ++h) {
            half8_t a[4], b[4];
            #pragma unroll
            for (int mi = 0; mi < 4; ++mi)
                a[mi] = *(const half8_t*)(As + (wm + mi * 16 + l15) * 64 +
                                          (((h * 4 + l4) ^ rs) << 3));
            #pragma unroll
            for (int ni = 0; ni < 4; ++ni)
                b[ni] = *(const half8_t*)(Bs + (wn + ni * 16 + l15) * 64 +
                                          (((h * 4 + l4) ^ rs) << 3));
            #pragma unroll
            for (int mi = 0; mi < 4; ++mi)
                #pragma unroll
                for (int ni = 0; ni < 4; ++ni)
                    acc[mi][ni] = MFMA16(a[mi], b[ni], acc[mi][ni]);
        }
        __syncthreads();
    }
}

// GEMM1: qkv = x @ w_qkv. 128x128 tiles; L2 half-N partition (R13/R14-verified).
// q -> qh natural (relu); k/v -> khT/vhT [bh][64][224] (pads zeroed).
__global__ __launch_bounds__(256, 4) void gemm_qkv_kernel(
    const _Float16* __restrict__ xh, const _Float16* __restrict__ wqkvT,
    const float* __restrict__ pos_enc,
    _Float16* __restrict__ qh, _Float16* __restrict__ khT, _Float16* __restrict__ vhT) {
    __shared__ _Float16 As[8192];
    __shared__ _Float16 Bs[8192];
    int bid = blockIdx.x;
    int xcd = bid & 7, i = bid >> 3;          // i in 0..881
    int xq = xcd & 3, nhalf = xcd >> 2;
    int mtl = i / 9, ntl = i - mtl * 9;       // mtl 0..97
    int mtile = xq * 98 + mtl;
    int ntile = nhalf * 9 + ntl;
    f32x4 acc[4][4];
    run_gemm128(xh, wqkvT, mtile * 128, ntile * 128, As, Bs, acc);

    const int tid = threadIdx.x;
    const int lane = tid & 63;
    const int wave = tid >> 6;
    const int wm = (wave >> 1) * 64;
    const int wn = (wave & 1) * 64;
    const int l15 = lane & 15;
    const int l4 = lane >> 4;

    const int s = ntile / 6;
    const int cb = (ntile - s * 6) * 128 + wn;

    if (s == 0) {
        #pragma unroll
        for (int mi = 0; mi < 4; ++mi) {
            #pragma unroll
            for (int ni = 0; ni < 4; ++ni) {
                int c = cb + ni * 16 + l15;
                int h = c >> 6, d = c & 63;
                #pragma unroll
                for (int r = 0; r < 4; ++r) {
                    int gr = mtile * 128 + wm + mi * 16 + l4 * 4 + r;
                    int b = gr / 196;
                    int n = gr - b * 196;
                    qh[((size_t)(b * 12 + h) * 196 + n) * 64 + d] =
                        (_Float16)fmaxf(acc[mi][ni][r], 0.f);
                }
            }
        }
    } else {
        _Float16* dstT = (s == 1) ? khT : vhT;
        #pragma unroll
        for (int mi = 0; mi < 4; ++mi) {
            int gr0 = mtile * 128 + wm + mi * 16 + l4 * 4;
            int b = gr0 / 196, n0 = gr0 - b * 196;
            #pragma unroll
            for (int ni = 0; ni < 4; ++ni) {
                int c = cb + ni * 16 + l15;
                int h = c >> 6, d = c & 63;
                _Float16* row = dstT + ((size_t)(b * 12 + h) * 64 + d) * 224;
                half4_t w;
                #pragma unroll
                for (int r = 0; r < 4; ++r) {
                    float v = acc[mi][ni][r];
                    if (s == 1) { v += pos_enc[(n0 + r) * 768 + c]; v = fmaxf(v, 0.f); }
                    w[r] = (_Float16)v;
                }
                *(half4_t*)(row + n0) = w;
                if (n0 == 192) {
                    half4_t z4 = {(_Float16)0.f, (_Float16)0.f, (_Float16)0.f, (_Float16)0.f};
                    #pragma unroll
                    for (int p = 196; p < 224; p += 4) *(half4_t*)(row + p) = z4;
                }
            }
        }
    }
}

// GEMM2: out = fused @ w_proj + b_proj (f32 out)
__global__ __launch_bounds__(256, 4) void gemm_proj_kernel(
    const _Float16* __restrict__ fused, const _Float16* __restrict__ wprojT,
    const float* __restrict__ b_proj, float* __restrict__ out) {
    __shared__ _Float16 As[8192];
    __shared__ _Float16 Bs[8192];
    int wgid = xcd_swizzle(blockIdx.x, 392 * 6);
    int mtile = wgid / 6, ntile = wgid - mtile * 6;
    f32x4 acc[4][4];
    run_gemm128(fused, wprojT, mtile * 128, ntile * 128, As, Bs, acc);

    const int tid = threadIdx.x;
    const int lane = tid & 63;
    const int wave = tid >> 6;
    const int wm = (wave >> 1) * 64;
    const int wn = (wave & 1) * 64;
    const int l15 = lane & 15;
    const int l4 = lane >> 4;

    #pragma unroll
    for (int mi = 0; mi < 4; ++mi) {
        #pragma unroll
        for (int ni = 0; ni < 4; ++ni) {
            int gc = ntile * 128 + wn + ni * 16 + l15;
            float bp = b_proj[gc];
            #pragma unroll
            for (int r = 0; r < 4; ++r) {
                int gr = mtile * 128 + wm + mi * 16 + l4 * 4 + r;
                out[(size_t)gr * 768 + gc] = acc[mi][ni][r] + bp;
            }
        }
    }
}

// ---------------- fused attention v3 (R14-verified) — now 4 blocks/CU ----------------
__global__ __launch_bounds__(512, 8) void attn_fused_kernel(
    const _Float16* __restrict__ qh, const _Float16* __restrict__ khT,
    const _Float16* __restrict__ vhT,
    const float* __restrict__ dwc_w, const float* __restrict__ dwc_b,
    _Float16* __restrict__ fused) {
    __shared__ _Float16 kv_l[64 * 64];
    __shared__ _Float16 pv[64 * 236];
    __shared__ float ksum[64];
    __shared__ float zz[196];

    int bh = blockIdx.x;
    int bb = bh / 12, hh = bh - bb * 12;
    int tid = threadIdx.x;
    int lane = tid & 63, wave = tid >> 6;
    int l15 = lane & 15, l4 = lane >> 4;
    size_t kbase = (size_t)bh * 14336;   // 64*224
    size_t qbase = (size_t)bh * 12544;

    // ---- ksum: wave w owns channels c = w*8..w*8+7; contiguous half4 + shfl reduce ----
    #pragma unroll
    for (int j = 0; j < 8; ++j) {
        int c = wave * 8 + j;
        float s = 0.f;
        if (lane < 49) {
            half4_t kq = *(const half4_t*)(khT + kbase + c * 224 + lane * 4);
            s = (float)kq[0] + (float)kq[1] + (float)kq[2] + (float)kq[3];
        }
        #pragma unroll
        for (int off = 32; off; off >>= 1) s += __shfl_down(s, off);
        if (lane == 0) ksum[c] = s;
    }

    // ---- kv = k^T v (64x64), frags from global; store kv_l swizzled ----
    {
        int ct = wave >> 1, dt0 = (wave & 1) * 2;
        const _Float16* ka  = khT + kbase + (ct * 16 + l15) * 224 + l4 * 8;
        const _Float16* vb0 = vhT + kbase + (dt0 * 16 + l15) * 224 + l4 * 8;
        const _Float16* vb1 = vb0 + 16 * 224;
        f32x4 acc0 = {0.f, 0.f, 0.f, 0.f}, acc1 = {0.f, 0.f, 0.f, 0.f};
        #pragma unroll
        for (int ks = 0; ks < 7; ++ks) {
            half8_t a  = *(const half8_t*)(ka + ks * 32);
            half8_t b0 = *(const half8_t*)(vb0 + ks * 32);
            half8_t b1 = *(const half8_t*)(vb1 + ks * 32);
            acc0 = MFMA16(a, b0, acc0);
            acc1 = MFMA16(a, b1, acc1);
        }
        half4_t h0, h1;
        #pragma unroll
        for (int r = 0; r < 4; ++r) { h0[r] = (_Float16)acc0[r]; h1[r] = (_Float16)acc1[r]; }
        int slot = ct * 2 + (l4 >> 1), sub = (l4 & 1) * 4;
        int d0 = dt0 * 16 + l15, d1 = d0 + 16;
        *(half4_t*)(kv_l + d0 * 64 + (((slot ^ (d0 & 7)) << 3) + sub)) = h0;
        *(half4_t*)(kv_l + d1 * 64 + (((slot ^ (d1 & 7)) << 3) + sub)) = h1;
    }
    __syncthreads();

    // ---- z ----
    if (tid < 196) {
        const _Float16* qrow = qh + qbase + tid * 64;
        float s = 0.f;
        #pragma unroll
        for (int c8 = 0; c8 < 8; ++c8) {
            half8_t qv = *(const half8_t*)(qrow + c8 * 8);
            #pragma unroll
            for (int j = 0; j < 8; ++j) s += (float)qv[j] * ksum[c8 * 8 + j];
        }
        zz[tid] = 1.0f / (s + 1e-6f);
    }
    __syncthreads();

    // ---- PV: pv[d][i] = zz[i] * (q @ kv), half4 writes ----
    for (int t = wave; t < 52; t += 8) {
        int mt = t >> 2, dt = t & 3;
        int d = dt * 16 + l15;
        f32x4 acc = {0.f, 0.f, 0.f, 0.f};
        const _Float16* qrow = qh + qbase + (mt * 16 + l15) * 64;
        half8_t a0 = *(const half8_t*)(qrow + l4 * 8);
        half8_t a1 = *(const half8_t*)(qrow + 32 + l4 * 8);
        half8_t b0 = *(const half8_t*)(kv_l + d * 64 + ((l4 ^ (d & 7)) << 3));
        half8_t b1 = *(const half8_t*)(kv_l + d * 64 + (((l4 + 4) ^ (d & 7)) << 3));
        acc = MFMA16(a0, b0, acc);
        acc = MFMA16(a1, b1, acc);
        int i0 = mt * 16 + l4 * 4;
        half4_t w;
        #pragma unroll
        for (int r = 0; r < 4; ++r) {
            int i = i0 + r;
            w[r] = (_Float16)(acc[r] * ((i < 196) ? zz[i] : 0.f));
        }
        *(half4_t*)(pv + d * 236 + i0) = w;
    }
    __syncthreads();

    // ---- conv (from global v rows) + combine pv + write fused ----
    #pragma unroll
    for (int rnd = 0; rnd < 2; ++rnd) {
        int y = rnd * 8 + wave;
        int d = lane;
        if (y < 14) {
            float cacc[14];
            float bd = dwc_b[d];
            #pragma unroll
            for (int x = 0; x < 14; ++x) cacc[x] = bd;
            const float* wrow = dwc_w + d * 25;
            #pragma unroll
            for (int ky = 0; ky < 5; ++ky) {
                int yy = y + ky - 2;
                if ((unsigned)yy < 14u) {
                    const _Float16* vr = vhT + kbase + d * 224 + yy * 14;
                    float hv[14];
                    #pragma unroll
                    for (int u = 0; u < 7; ++u) {
                        half2_t w2 = *(const half2_t*)(vr + u * 2);
                        hv[2 * u] = (float)w2[0];
                        hv[2 * u + 1] = (float)w2[1];
                    }
                    #pragma unroll
                    for (int kx = 0; kx < 5; ++kx) {
                        float wk = wrow[ky * 5 + kx];
                        #pragma unroll
                        for (int x = 0; x < 14; ++x) {
                            int c = x + kx - 2;          // compile-time per (x,kx)
                            if (c >= 0 && c < 14) cacc[x] += hv[c] * wk;
                        }
                    }
                }
            }
            int ibase = y * 14;
            _Float16* orow = fused + ((size_t)bb * 196 + ibase) * 768 + hh * 64 + d;
            #pragma unroll
            for (int xp = 0; xp < 7; ++xp) {
                half2_t pw = *(const half2_t*)(pv + d * 236 + ibase + 2 * xp);
                orow[(2 * xp) * 768]     = (_Float16)((float)pw[0] + cacc[2 * xp]);
                orow[(2 * xp + 1) * 768] = (_Float16)((float)pw[1] + cacc[2 * xp + 1]);
            }
        }
    }
}

// ---------------- launcher ----------------

extern "C" void kernel_launch(void* const* d_in, const int* in_sizes, int n_in,
                              void* d_out, int out_size, void* d_ws, size_t ws_size,
                              hipStream_t stream) {
    const float* x       = (const float*)d_in[0];
    const float* w_qkv   = (const float*)d_in[1];
    const float* pos_enc = (const float*)d_in[2];
    const float* dwc_w   = (const float*)d_in[3];
    const float* dwc_b   = (const float*)d_in[4];
    const float* w_proj  = (const float*)d_in[5];
    const float* b_proj  = (const float*)d_in[6];

    const size_t NEEDED = 335020032;
    if (ws_size < NEEDED) return;  // insufficient scratch; bail

    char* ws = (char*)d_ws;
    _Float16* xh     = (_Float16*)(ws + 0);          // 77,070,336 B (also 'fused' later)
    _Float16* fused  = xh;                           // safe: attn reads qh/khT/vhT only
    _Float16* wqkvT  = (_Float16*)(ws + 77070336);   // 3,538,944
    _Float16* wprojT = (_Float16*)(ws + 80609280);   // 1,179,648
    _Float16* qh     = (_Float16*)(ws + 81788928);   // 77,070,336  natural [bh][196][64]
    _Float16* khT    = (_Float16*)(ws + 158859264);  // 88,080,384  [bh][64][224]
    _Float16* vhT    = (_Float16*)(ws + 246939648);  // 88,080,384  [bh][64][224]

    prep_kernel<<<4096 + 6912 + 2304, 256, 0, stream>>>(x, xh, w_qkv, wqkvT, w_proj, wprojT);
    gemm_qkv_kernel<<<392 * 18, 256, 0, stream>>>(xh, wqkvT, pos_enc, qh, khT, vhT);
    attn_fused_kernel<<<3072, 512, 0, stream>>>(qh, khT, vhT, dwc_w, dwc_b, fused);
    gemm_proj_kernel<<<392 * 6, 256, 0, stream>>>(fused, wprojT, b_proj, (float*)d_out);
}

// Round 18
// 583.270 us; speedup vs baseline: 1.0628x; 1.0628x over previous
//
#include <hip/hip_runtime.h>

typedef _Float16 half8_t __attribute__((ext_vector_type(8)));
typedef _Float16 half4_t __attribute__((ext_vector_type(4)));
typedef _Float16 half2_t __attribute__((ext_vector_type(2)));
typedef float f32x4 __attribute__((ext_vector_type(4)));

#define MFMA16(a, b, c) __builtin_amdgcn_mfma_f32_16x16x32_f16((a), (b), (c), 0, 0, 0)

typedef const unsigned int __attribute__((address_space(1)))* gas_ptr;
typedef unsigned int __attribute__((address_space(3)))* las_ptr;

__device__ __forceinline__ void gload16(const void* g, void* l) {
    __builtin_amdgcn_global_load_lds((gas_ptr)g, (las_ptr)l, 16, 0, 0);
}

// m204 bijective XCD swizzle: contiguous wgid chunk per XCD
__device__ __forceinline__ int xcd_swizzle(int bid, int nwg) {
    int xcd = bid & 7, i = bid >> 3;
    int q = nwg >> 3, r = nwg & 7;
    return (xcd < r ? xcd * (q + 1) : r * (q + 1) + (xcd - r) * q) + i;
}

// ---------------- convert / transpose ----------------

__global__ void cvt_f2h_kernel(const float* __restrict__ in, _Float16* __restrict__ out, int n4) {
    int stride = gridDim.x * blockDim.x;
    for (int i = blockIdx.x * blockDim.x + threadIdx.x; i < n4; i += stride) {
        f32x4 v = *(const f32x4*)(in + (size_t)4 * i);
        half4_t h;
        h[0] = (_Float16)v[0]; h[1] = (_Float16)v[1];
        h[2] = (_Float16)v[2]; h[3] = (_Float16)v[3];
        *(half4_t*)(out + (size_t)4 * i) = h;
    }
}

// out[j][k] = in[k][j], K fixed at 768
__global__ void transpose768_kernel(const float* __restrict__ in, _Float16* __restrict__ out, int ncols) {
    int idx = blockIdx.x * 256 + threadIdx.x;
    int total = ncols * 768;
    if (idx < total) {
        int j = idx / 768;
        int k = idx - j * 768;
        out[idx] = (_Float16)in[(size_t)k * ncols + j];
    }
}

// ---------------- GEMM core: m97-class 128x128 tile, 4 waves, BK=64, single-buffer ----
// (R12/R13/R14-verified best: 0 conflicts, 4 blocks/CU, MfmaUtil 28.5%)

#define STG128(kof)                                                               \
    {                                                                             \
        _Pragma("unroll")                                                         \
        for (int i = 0; i < 4; ++i) {                                             \
            gload16(ArowS + (kof) + i * 24576, As + wave * 512 + i * 2048);       \
            gload16(BrowS + (kof) + i * 24576, Bs + wave * 512 + i * 2048);       \
        }                                                                         \
    }

__device__ __forceinline__ void run_gemm128(const _Float16* __restrict__ A,
                                            const _Float16* __restrict__ Bt,
                                            int mbase, int nbase,
                                            _Float16* As, _Float16* Bs,   // 8192 f16 each
                                            f32x4 (&acc)[4][4]) {
    const int tid = threadIdx.x;
    const int lane = tid & 63;
    const int wave = tid >> 6;
    const int wm = (wave >> 1) * 64;
    const int wn = (wave & 1) * 64;
    const int l15 = lane & 15;
    const int l4 = lane >> 4;
    const int rs = l15 & 7;                                   // read swizzle key
    const int srow = lane >> 3;                               // staging row-in-8 (0..7)
    const int ssl = ((lane & 7) ^ srow) << 3;                 // staging source slot offset

    #pragma unroll
    for (int mi = 0; mi < 4; ++mi)
        #pragma unroll
        for (int ni = 0; ni < 4; ++ni)
            acc[mi][ni] = (f32x4){0.f, 0.f, 0.f, 0.f};

    const _Float16* ArowS = A + (size_t)(mbase + wave * 8 + srow) * 768 + ssl;
    const _Float16* BrowS = Bt + (size_t)(nbase + wave * 8 + srow) * 768 + ssl;

    for (int kt = 0; kt < 12; ++kt) {
        STG128(kt * 64)
        __syncthreads();
        #pragma unroll
        for (int h = 0; h < 2; ++h) {
            half8_t a[4], b[4];
            #pragma unroll
            for (int mi = 0; mi < 4; ++mi)
                a[mi] = *(const half8_t*)(As + (wm + mi * 16 + l15) * 64 +
                                          (((h * 4 + l4) ^ rs) << 3));
            #pragma unroll
            for (int ni = 0; ni < 4; ++ni)
                b[ni] = *(const half8_t*)(Bs + (wn + ni * 16 + l15) * 64 +
                                          (((h * 4 + l4) ^ rs) << 3));
            #pragma unroll
            for (int mi = 0; mi < 4; ++mi)
                #pragma unroll
                for (int ni = 0; ni < 4; ++ni)
                    acc[mi][ni] = MFMA16(a[mi], b[ni], acc[mi][ni]);
        }
        __syncthreads();
    }
}

// GEMM1: qkv = x @ w_qkv. 128x128 tiles; L2 half-N partition (R13/R14-verified:
// xq owns a 98-mtile band, nhalf owns ntiles 0-8 / 9-17; 8 x 882 = 7056 bijective).
// q -> qh natural (relu); k/v -> khT/vhT [bh][64][224] (pads zeroed).
__global__ __launch_bounds__(256, 4) void gemm_qkv_kernel(
    const _Float16* __restrict__ xh, const _Float16* __restrict__ wqkvT,
    const float* __restrict__ pos_enc,
    _Float16* __restrict__ qh, _Float16* __restrict__ khT, _Float16* __restrict__ vhT) {
    __shared__ _Float16 As[8192];
    __shared__ _Float16 Bs[8192];
    int bid = blockIdx.x;
    int xcd = bid & 7, i = bid >> 3;          // i in 0..881
    int xq = xcd & 3, nhalf = xcd >> 2;
    int mtl = i / 9, ntl = i - mtl * 9;       // mtl 0..97
    int mtile = xq * 98 + mtl;
    int ntile = nhalf * 9 + ntl;
    f32x4 acc[4][4];
    run_gemm128(xh, wqkvT, mtile * 128, ntile * 128, As, Bs, acc);

    const int tid = threadIdx.x;
    const int lane = tid & 63;
    const int wave = tid >> 6;
    const int wm = (wave >> 1) * 64;
    const int wn = (wave & 1) * 64;
    const int l15 = lane & 15;
    const int l4 = lane >> 4;

    const int s = ntile / 6;
    const int cb = (ntile - s * 6) * 128 + wn;

    if (s == 0) {
        #pragma unroll
        for (int mi = 0; mi < 4; ++mi) {
            #pragma unroll
            for (int ni = 0; ni < 4; ++ni) {
                int c = cb + ni * 16 + l15;
                int h = c >> 6, d = c & 63;
                #pragma unroll
                for (int r = 0; r < 4; ++r) {
                    int gr = mtile * 128 + wm + mi * 16 + l4 * 4 + r;
                    int b = gr / 196;
                    int n = gr - b * 196;
                    qh[((size_t)(b * 12 + h) * 196 + n) * 64 + d] =
                        (_Float16)fmaxf(acc[mi][ni][r], 0.f);
                }
            }
        }
    } else {
        _Float16* dstT = (s == 1) ? khT : vhT;
        #pragma unroll
        for (int mi = 0; mi < 4; ++mi) {
            int gr0 = mtile * 128 + wm + mi * 16 + l4 * 4;
            int b = gr0 / 196, n0 = gr0 - b * 196;
            #pragma unroll
            for (int ni = 0; ni < 4; ++ni) {
                int c = cb + ni * 16 + l15;
                int h = c >> 6, d = c & 63;
                _Float16* row = dstT + ((size_t)(b * 12 + h) * 64 + d) * 224;
                half4_t w;
                #pragma unroll
                for (int r = 0; r < 4; ++r) {
                    float v = acc[mi][ni][r];
                    if (s == 1) { v += pos_enc[(n0 + r) * 768 + c]; v = fmaxf(v, 0.f); }
                    w[r] = (_Float16)v;
                }
                *(half4_t*)(row + n0) = w;
                if (n0 == 192) {
                    half4_t z4 = {(_Float16)0.f, (_Float16)0.f, (_Float16)0.f, (_Float16)0.f};
                    #pragma unroll
                    for (int p = 196; p < 224; p += 4) *(half4_t*)(row + p) = z4;
                }
            }
        }
    }
}

// GEMM2: out = fused @ w_proj + b_proj (f32 out)
__global__ __launch_bounds__(256, 4) void gemm_proj_kernel(
    const _Float16* __restrict__ fused, const _Float16* __restrict__ wprojT,
    const float* __restrict__ b_proj, float* __restrict__ out) {
    __shared__ _Float16 As[8192];
    __shared__ _Float16 Bs[8192];
    int wgid = xcd_swizzle(blockIdx.x, 392 * 6);
    int mtile = wgid / 6, ntile = wgid - mtile * 6;
    f32x4 acc[4][4];
    run_gemm128(fused, wprojT, mtile * 128, ntile * 128, As, Bs, acc);

    const int tid = threadIdx.x;
    const int lane = tid & 63;
    const int wave = tid >> 6;
    const int wm = (wave >> 1) * 64;
    const int wn = (wave & 1) * 64;
    const int l15 = lane & 15;
    const int l4 = lane >> 4;

    #pragma unroll
    for (int mi = 0; mi < 4; ++mi) {
        #pragma unroll
        for (int ni = 0; ni < 4; ++ni) {
            int gc = ntile * 128 + wn + ni * 16 + l15;
            float bp = b_proj[gc];
            #pragma unroll
            for (int r = 0; r < 4; ++r) {
                int gr = mtile * 128 + wm + mi * 16 + l4 * 4 + r;
                out[(size_t)gr * 768 + gc] = acc[mi][ni][r] + bp;
            }
        }
    }
}

// ---------------- fused attention v3 (R14-verified): no LDS staging, global-frag MFMA ----
__global__ __launch_bounds__(512, 6) void attn_fused_kernel(
    const _Float16* __restrict__ qh, const _Float16* __restrict__ khT,
    const _Float16* __restrict__ vhT,
    const float* __restrict__ dwc_w, const float* __restrict__ dwc_b,
    _Float16* __restrict__ fused) {
    __shared__ _Float16 kv_l[64 * 64];
    __shared__ _Float16 pv[64 * 236];
    __shared__ float ksum[64];
    __shared__ float zz[196];

    int bh = blockIdx.x;
    int bb = bh / 12, hh = bh - bb * 12;
    int tid = threadIdx.x;
    int lane = tid & 63, wave = tid >> 6;
    int l15 = lane & 15, l4 = lane >> 4;
    size_t kbase = (size_t)bh * 14336;   // 64*224
    size_t qbase = (size_t)bh * 12544;

    // ---- ksum: wave w owns channels c = w*8..w*8+7; contiguous half4 + shfl reduce ----
    #pragma unroll
    for (int j = 0; j < 8; ++j) {
        int c = wave * 8 + j;
        float s = 0.f;
        if (lane < 49) {
            half4_t kq = *(const half4_t*)(khT + kbase + c * 224 + lane * 4);
            s = (float)kq[0] + (float)kq[1] + (float)kq[2] + (float)kq[3];
        }
        #pragma unroll
        for (int off = 32; off; off >>= 1) s += __shfl_down(s, off);
        if (lane == 0) ksum[c] = s;
    }

    // ---- kv = k^T v (64x64), frags from global; store kv_l swizzled ----
    {
        int ct = wave >> 1, dt0 = (wave & 1) * 2;
        const _Float16* ka  = khT + kbase + (ct * 16 + l15) * 224 + l4 * 8;
        const _Float16* vb0 = vhT + kbase + (dt0 * 16 + l15) * 224 + l4 * 8;
        const _Float16* vb1 = vb0 + 16 * 224;
        f32x4 acc0 = {0.f, 0.f, 0.f, 0.f}, acc1 = {0.f, 0.f, 0.f, 0.f};
        #pragma unroll
        for (int ks = 0; ks < 7; ++ks) {
            half8_t a  = *(const half8_t*)(ka + ks * 32);
            half8_t b0 = *(const half8_t*)(vb0 + ks * 32);
            half8_t b1 = *(const half8_t*)(vb1 + ks * 32);
            acc0 = MFMA16(a, b0, acc0);
            acc1 = MFMA16(a, b1, acc1);
        }
        half4_t h0, h1;
        #pragma unroll
        for (int r = 0; r < 4; ++r) { h0[r] = (_Float16)acc0[r]; h1[r] = (_Float16)acc1[r]; }
        int slot = ct * 2 + (l4 >> 1), sub = (l4 & 1) * 4;
        int d0 = dt0 * 16 + l15, d1 = d0 + 16;
        *(half4_t*)(kv_l + d0 * 64 + (((slot ^ (d0 & 7)) << 3) + sub)) = h0;
        *(half4_t*)(kv_l + d1 * 64 + (((slot ^ (d1 & 7)) << 3) + sub)) = h1;
    }
    __syncthreads();

    // ---- z ----
    if (tid < 196) {
        const _Float16* qrow = qh + qbase + tid * 64;
        float s = 0.f;
        #pragma unroll
        for (int c8 = 0; c8 < 8; ++c8) {
            half8_t qv = *(const half8_t*)(qrow + c8 * 8);
            #pragma unroll
            for (int j = 0; j < 8; ++j) s += (float)qv[j] * ksum[c8 * 8 + j];
        }
        zz[tid] = 1.0f / (s + 1e-6f);
    }
    __syncthreads();

    // ---- PV: pv[d][i] = zz[i] * (q @ kv), half4 writes ----
    for (int t = wave; t < 52; t += 8) {
        int mt = t >> 2, dt = t & 3;
        int d = dt * 16 + l15;
        f32x4 acc = {0.f, 0.f, 0.f, 0.f};
        const _Float16* qrow = qh + qbase + (mt * 16 + l15) * 64;
        half8_t a0 = *(const half8_t*)(qrow + l4 * 8);
        half8_t a1 = *(const half8_t*)(qrow + 32 + l4 * 8);
        half8_t b0 = *(const half8_t*)(kv_l + d * 64 + ((l4 ^ (d & 7)) << 3));
        half8_t b1 = *(const half8_t*)(kv_l + d * 64 + (((l4 + 4) ^ (d & 7)) << 3));
        acc = MFMA16(a0, b0, acc);
        acc = MFMA16(a1, b1, acc);
        int i0 = mt * 16 + l4 * 4;
        half4_t w;
        #pragma unroll
        for (int r = 0; r < 4; ++r) {
            int i = i0 + r;
            w[r] = (_Float16)(acc[r] * ((i < 196) ? zz[i] : 0.f));
        }
        *(half4_t*)(pv + d * 236 + i0) = w;
    }
    __syncthreads();

    // ---- conv (from global v rows) + combine pv + write fused ----
    #pragma unroll
    for (int rnd = 0; rnd < 2; ++rnd) {
        int y = rnd * 8 + wave;
        int d = lane;
        if (y < 14) {
            float cacc[14];
            float bd = dwc_b[d];
            #pragma unroll
            for (int x = 0; x < 14; ++x) cacc[x] = bd;
            const float* wrow = dwc_w + d * 25;
            #pragma unroll
            for (int ky = 0; ky < 5; ++ky) {
                int yy = y + ky - 2;
                if ((unsigned)yy < 14u) {
                    const _Float16* vr = vhT + kbase + d * 224 + yy * 14;
                    float hv[14];
                    #pragma unroll
                    for (int u = 0; u < 7; ++u) {
                        half2_t w2 = *(const half2_t*)(vr + u * 2);
                        hv[2 * u] = (float)w2[0];
                        hv[2 * u + 1] = (float)w2[1];
                    }
                    #pragma unroll
                    for (int kx = 0; kx < 5; ++kx) {
                        float wk = wrow[ky * 5 + kx];
                        #pragma unroll
                        for (int x = 0; x < 14; ++x) {
                            int c = x + kx - 2;          // compile-time per (x,kx)
                            if (c >= 0 && c < 14) cacc[x] += hv[c] * wk;
                        }
                    }
                }
            }
            int ibase = y * 14;
            _Float16* orow = fused + ((size_t)bb * 196 + ibase) * 768 + hh * 64 + d;
            #pragma unroll
            for (int xp = 0; xp < 7; ++xp) {
                half2_t pw = *(const half2_t*)(pv + d * 236 + ibase + 2 * xp);
                orow[(2 * xp) * 768]     = (_Float16)((float)pw[0] + cacc[2 * xp]);
                orow[(2 * xp + 1) * 768] = (_Float16)((float)pw[1] + cacc[2 * xp + 1]);
            }
        }
    }
}

// ---------------- launcher ----------------

extern "C" void kernel_launch(void* const* d_in, const int* in_sizes, int n_in,
                              void* d_out, int out_size, void* d_ws, size_t ws_size,
                              hipStream_t stream) {
    const float* x       = (const float*)d_in[0];
    const float* w_qkv   = (const float*)d_in[1];
    const float* pos_enc = (const float*)d_in[2];
    const float* dwc_w   = (const float*)d_in[3];
    const float* dwc_b   = (const float*)d_in[4];
    const float* w_proj  = (const float*)d_in[5];
    const float* b_proj  = (const float*)d_in[6];

    const size_t NEEDED = 335020032;
    if (ws_size < NEEDED) return;  // insufficient scratch; bail

    char* ws = (char*)d_ws;
    _Float16* xh     = (_Float16*)(ws + 0);          // 77,070,336 B (also 'fused' later)
    _Float16* fused  = xh;                           // safe: attn reads qh/khT/vhT only
    _Float16* wqkvT  = (_Float16*)(ws + 77070336);   // 3,538,944
    _Float16* wprojT = (_Float16*)(ws + 80609280);   // 1,179,648
    _Float16* qh     = (_Float16*)(ws + 81788928);   // 77,070,336  natural [bh][196][64]
    _Float16* khT    = (_Float16*)(ws + 158859264);  // 88,080,384  [bh][64][224]
    _Float16* vhT    = (_Float16*)(ws + 246939648);  // 88,080,384  [bh][64][224]

    cvt_f2h_kernel<<<4096, 256, 0, stream>>>(x, xh, 9633792);
    transpose768_kernel<<<(2304 * 768 + 255) / 256, 256, 0, stream>>>(w_qkv, wqkvT, 2304);
    transpose768_kernel<<<(768 * 768 + 255) / 256, 256, 0, stream>>>(w_proj, wprojT, 768);
    gemm_qkv_kernel<<<392 * 18, 256, 0, stream>>>(xh, wqkvT, pos_enc, qh, khT, vhT);
    attn_fused_kernel<<<3072, 512, 0, stream>>>(qh, khT, vhT, dwc_w, dwc_b, fused);
    gemm_proj_kernel<<<392 * 6, 256, 0, stream>>>(fused, wprojT, b_proj, (float*)d_out);
}